// Round 8
// baseline (183.954 us; speedup 1.0000x reference)
//
#include <hip/hip_runtime.h>
#include <hip/hip_bf16.h>

typedef __bf16 bf16x8 __attribute__((ext_vector_type(8)));
typedef __bf16 bf16x4 __attribute__((ext_vector_type(4)));
typedef float f32x4 __attribute__((ext_vector_type(4)));
typedef unsigned short u16x8 __attribute__((ext_vector_type(8)));

// B=128, T=256, D=512, H=8, HD=64. M = B*T = 32768.

__device__ __forceinline__ unsigned short f2bf(float f) {
  unsigned u = __float_as_uint(f);
  u += 0x7fffu + ((u >> 16) & 1u);   // RNE
  return (unsigned short)(u >> 16);
}

__device__ __forceinline__ bf16x4 cvt4(f32x4 v) {
  bf16x4 o;
  o[0] = (__bf16)v[0]; o[1] = (__bf16)v[1]; o[2] = (__bf16)v[2]; o[3] = (__bf16)v[3];
  return o;
}

// async global->LDS, 16B per lane. LDS dest wave-uniform; HW adds lane*16.
__device__ __forceinline__ void async16(const void* g, void* l) {
  __builtin_amdgcn_global_load_lds(
      (const __attribute__((address_space(1))) void*)g,
      (__attribute__((address_space(3))) void*)l, 16, 0, 0);
}

// ---------------- x fp32 -> bf16 ----------------
__global__ __launch_bounds__(256) void k_convert_x(const float* __restrict__ in,
                                                   unsigned short* __restrict__ out) {
  int i = blockIdx.x * 256 + threadIdx.x;
  const float4* p = (const float4*)in + (size_t)i * 2;
  float4 a = p[0], b = p[1];
  u16x8 o;
  o[0] = f2bf(a.x); o[1] = f2bf(a.y); o[2] = f2bf(a.z); o[3] = f2bf(a.w);
  o[4] = f2bf(b.x); o[5] = f2bf(b.y); o[6] = f2bf(b.z); o[7] = f2bf(b.w);
  *((u16x8*)out + i) = o;
}

// ---------------- Wq/Wk/Wv fp32 [512][64] -> bf16 [64][512], 3 weights in one launch ----------------
__global__ __launch_bounds__(256) void k_transpose_w3(const float* __restrict__ w0,
                                                      const float* __restrict__ w1,
                                                      const float* __restrict__ w2,
                                                      unsigned short* __restrict__ out) {
  __shared__ unsigned short tile[64][72];
  int z = blockIdx.z;
  int wsel = z >> 3, hsel = z & 7;
  const float* inb = (wsel == 0 ? w0 : (wsel == 1 ? w1 : w2)) + (size_t)hsel * 512 * 64;
  unsigned short* outb = out + (size_t)z * 512 * 64;
  int r0 = blockIdx.y * 64;
  int tid = threadIdx.x;
  int r = tid >> 2, cq = (tid & 3) * 16;
  const float* src = inb + (size_t)(r0 + r) * 64 + cq;
#pragma unroll
  for (int i = 0; i < 16; i += 4) {
    float4 v = *(const float4*)(src + i);
    tile[r][cq + i + 0] = f2bf(v.x);
    tile[r][cq + i + 1] = f2bf(v.y);
    tile[r][cq + i + 2] = f2bf(v.z);
    tile[r][cq + i + 3] = f2bf(v.w);
  }
  __syncthreads();
  int cr = tid >> 2, rq = (tid & 3) * 16;
  u16x8 o0, o1;
#pragma unroll
  for (int i = 0; i < 8; ++i) o0[i] = tile[rq + i][cr];
#pragma unroll
  for (int i = 0; i < 8; ++i) o1[i] = tile[rq + 8 + i][cr];
  unsigned short* dst = outb + (size_t)cr * 512 + r0 + rq;
  *(u16x8*)dst = o0;
  *(u16x8*)(dst + 8) = o1;
}

// ---------------- Wo fp32 [512][512] -> bf16 [512][512]^T ----------------
__global__ __launch_bounds__(256) void k_transpose_w(const float* __restrict__ in,
                                                     unsigned short* __restrict__ out,
                                                     int rows, int cols) {
  __shared__ unsigned short tile[64][72];
  int c0 = blockIdx.x * 64, r0 = blockIdx.y * 64;
  int tid = threadIdx.x;
  int r = tid >> 2, cq = (tid & 3) * 16;
  const float* src = in + (size_t)(r0 + r) * cols + c0 + cq;
#pragma unroll
  for (int i = 0; i < 16; i += 4) {
    float4 v = *(const float4*)(src + i);
    tile[r][cq + i + 0] = f2bf(v.x);
    tile[r][cq + i + 1] = f2bf(v.y);
    tile[r][cq + i + 2] = f2bf(v.z);
    tile[r][cq + i + 3] = f2bf(v.w);
  }
  __syncthreads();
  int cr = tid >> 2, rq = (tid & 3) * 16;
  u16x8 o0, o1;
#pragma unroll
  for (int i = 0; i < 8; ++i) o0[i] = tile[rq + i][cr];
#pragma unroll
  for (int i = 0; i < 8; ++i) o1[i] = tile[rq + 8 + i][cr];
  unsigned short* dst = out + (size_t)(c0 + cr) * rows + r0 + rq;
  *(u16x8*)dst = o0;
  *(u16x8*)(dst + 8) = o1;
}

// ---------------- 256x256x(K=512) GEMM, 2 barrier-intervals per K-tile ----------------
// Region 1: all 24 ds_reads + 32 MFMA (compiler interleaves; lgkm-drain + barrier).
// Region 2: stage tile t+2 (8 async16, issued early) + 32 MFMA + vmcnt(8) + barrier.
// KIND 0: x*Wqk^T -> Q,K [B,H,T,HD] (swapped mfma: packed hd stores). grid 512.
// KIND 1: a*Wo^T + bo -> fp32 out (swapped mfma: packed float4 stores). grid 256.
// KIND 2: x*Wv^T -> V^T [B,H,HD,T] (normal mfma: packed t stores).     grid 256.
template <int KIND>
__global__ __launch_bounds__(512, 1) void k_gemmP(
    const unsigned short* __restrict__ A,
    const unsigned short* __restrict__ Bmat,
    unsigned short* __restrict__ O0,
    unsigned short* __restrict__ O1,
    const float* __restrict__ bo,
    float* __restrict__ outf) {
  __shared__ unsigned short smem[65536];   // 128 KiB: 2 bufs x (A0|A1|B0|B1) x 16 KiB
  const int P = (KIND == 0) ? 64 : 32;     // blocks per XCD
  int xcd = blockIdx.x & 7, g = blockIdx.x >> 3;
  int w = xcd * P + g;
  int mt, nt;
  if (KIND == 0) { mt = w >> 2; nt = w & 3; }
  else           { mt = w >> 1; nt = w & 1; }
  int m0 = mt * 256, n0 = nt * 256;
  int tid = threadIdx.x;
  int wid = tid >> 6, lane = tid & 63;
  int lr = lane & 15, lg = lane >> 4;
  int wm = wid >> 2, wn = wid & 3;

  int srow = wid * 16 + (lane >> 3);
  int scs = (lane & 7) ^ (lane >> 3);         // swizzled 16B-chunk index (rule 21 inverse)
  auto stage_tile = [&](int kb, int buf) {
#pragma unroll
    for (int H = 0; H < 4; ++H) {
      const unsigned short* gb = (H < 2) ? (A + (size_t)(m0 + H * 128) * 512)
                                         : (Bmat + (size_t)(n0 + (H - 2) * 128) * 512);
#pragma unroll
      for (int j = 0; j < 2; ++j) {
        int row = srow + j * 8;
        async16(gb + (size_t)row * 512 + kb * 64 + scs * 8,
                smem + buf * 32768 + H * 8192 + (wid * 2 + j) * 512);
      }
    }
  };
  int xcol0 = ((0 * 64 + lg * 16) ^ ((lr & 7) * 16)) >> 1;
  int xcol1 = ((1 * 64 + lg * 16) ^ ((lr & 7) * 16)) >> 1;
  auto lda = [&](int buf, int mi, int k32) -> bf16x8 {
    int off = buf * 32768 + wm * 8192 + (mi * 16 + lr) * 64 + (k32 ? xcol1 : xcol0);
    return *(const bf16x8*)&smem[off];
  };
  auto ldb = [&](int buf, int ni, int k32) -> bf16x8 {
    int n = wn * 64 + ni * 16 + lr;
    int off = buf * 32768 + 16384 + (n >> 7) * 8192 + (n & 127) * 64 + (k32 ? xcol1 : xcol0);
    return *(const bf16x8*)&smem[off];
  };

  f32x4 acc[8][4];
#pragma unroll
  for (int mi = 0; mi < 8; ++mi)
#pragma unroll
    for (int ni = 0; ni < 4; ++ni) acc[mi][ni] = (f32x4){0.f, 0.f, 0.f, 0.f};

#define MF(dst, afrag, bfrag)                                                        \
  if constexpr (KIND == 2)                                                           \
    dst = __builtin_amdgcn_mfma_f32_16x16x32_bf16(afrag, bfrag, dst, 0, 0, 0);       \
  else                                                                               \
    dst = __builtin_amdgcn_mfma_f32_16x16x32_bf16(bfrag, afrag, dst, 0, 0, 0);

  stage_tile(0, 0);
  stage_tile(1, 1);
  asm volatile("s_waitcnt vmcnt(8)" ::: "memory");
  __builtin_amdgcn_s_barrier();
  asm volatile("" ::: "memory");

  bf16x8 a03[4][2], a47[4][2], b01[2][2], b23[2][2];
#pragma unroll
  for (int t = 0; t < 8; ++t) {
    int buf = t & 1;
    // ---- Region 1: all LDS reads of tile t + first 32 MFMA ----
#pragma unroll
    for (int mi = 0; mi < 4; ++mi) {
      a03[mi][0] = lda(buf, mi, 0);     a03[mi][1] = lda(buf, mi, 1);
      a47[mi][0] = lda(buf, mi + 4, 0); a47[mi][1] = lda(buf, mi + 4, 1);
    }
#pragma unroll
    for (int ni = 0; ni < 2; ++ni) {
      b01[ni][0] = ldb(buf, ni, 0);     b01[ni][1] = ldb(buf, ni, 1);
      b23[ni][0] = ldb(buf, ni + 2, 0); b23[ni][1] = ldb(buf, ni + 2, 1);
    }
    __builtin_amdgcn_s_setprio(1);
#pragma unroll
    for (int mi = 0; mi < 4; ++mi)
#pragma unroll
      for (int ni = 0; ni < 2; ++ni)
#pragma unroll
        for (int k = 0; k < 2; ++k) { MF(acc[mi][ni], a03[mi][k], b01[ni][k]); }
#pragma unroll
    for (int mi = 0; mi < 4; ++mi)
#pragma unroll
      for (int ni = 0; ni < 2; ++ni)
#pragma unroll
        for (int k = 0; k < 2; ++k) { MF(acc[mi + 4][ni], a47[mi][k], b01[ni][k]); }
    __builtin_amdgcn_s_setprio(0);
    // all of buf's reads complete per-wave, then sync -> buf is free for staging
    asm volatile("s_waitcnt lgkmcnt(0)" ::: "memory");
    __builtin_amdgcn_s_barrier();
    asm volatile("" ::: "memory");
    // ---- Region 2: stage tile t+2 into buf + last 32 MFMA ----
    if (t < 6) stage_tile(t + 2, buf);
    __builtin_amdgcn_s_setprio(1);
#pragma unroll
    for (int mi = 0; mi < 4; ++mi)
#pragma unroll
      for (int ni = 0; ni < 2; ++ni)
#pragma unroll
        for (int k = 0; k < 2; ++k) { MF(acc[mi][ni + 2], a03[mi][k], b23[ni][k]); }
#pragma unroll
    for (int mi = 0; mi < 4; ++mi)
#pragma unroll
      for (int ni = 0; ni < 2; ++ni)
#pragma unroll
        for (int k = 0; k < 2; ++k) { MF(acc[mi + 4][ni + 2], a47[mi][k], b23[ni][k]); }
    __builtin_amdgcn_s_setprio(0);
    // counted wait: tile t+1 landed (t+2's 8 loads stay in flight)
    if (t < 6)       asm volatile("s_waitcnt vmcnt(8)" ::: "memory");
    else if (t == 6) asm volatile("s_waitcnt vmcnt(0)" ::: "memory");
    asm volatile("" ::: "memory");
    __builtin_amdgcn_s_barrier();
    asm volatile("" ::: "memory");
  }
#undef MF

  // ---- epilogues (write straight from acc; no LDS use) ----
  if constexpr (KIND == 0) {
    int z = n0 >> 9;
    int h = ((n0 + wn * 64) >> 6) & 7;
    unsigned short* outp = (z ? O1 : O0) + (size_t)(mt * 8 + h) * 16384;
#pragma unroll
    for (int ni = 0; ni < 4; ++ni) {
      int hd0 = ni * 16 + lg * 4;
#pragma unroll
      for (int mi = 0; mi < 8; ++mi) {
        int tq = wm * 128 + mi * 16 + lr;
        *(bf16x4*)&outp[(size_t)tq * 64 + hd0] = cvt4(acc[mi][ni]);
      }
    }
  } else if constexpr (KIND == 1) {
#pragma unroll
    for (int ni = 0; ni < 4; ++ni) {
      int nb = n0 + wn * 64 + ni * 16 + lg * 4;
      float4 b4 = *(const float4*)&bo[nb];
#pragma unroll
      for (int mi = 0; mi < 8; ++mi) {
        int mg = m0 + wm * 128 + mi * 16 + lr;
        float4 o;
        o.x = acc[mi][ni][0] + b4.x; o.y = acc[mi][ni][1] + b4.y;
        o.z = acc[mi][ni][2] + b4.z; o.w = acc[mi][ni][3] + b4.w;
        *(float4*)&outf[(size_t)mg * 512 + nb] = o;
      }
    }
  } else {
    int h = (n0 >> 6) + wn;
    unsigned short* outp = O0 + (size_t)(mt * 8 + h) * 16384;
#pragma unroll
    for (int ni = 0; ni < 4; ++ni) {
      int hd = ni * 16 + lr;
#pragma unroll
      for (int mi = 0; mi < 8; ++mi) {
        int tq = wm * 128 + mi * 16 + lg * 4;
        *(bf16x4*)&outp[(size_t)hd * 256 + tq] = cvt4(acc[mi][ni]);
      }
    }
  }
}

// ---------------- fused causal attention v2: LDS K/V, balanced chunk pairs ----------------
__global__ __launch_bounds__(512, 1) void k_attn2(
    const unsigned short* __restrict__ Qb,
    const unsigned short* __restrict__ Kb,
    const unsigned short* __restrict__ Vtb,
    unsigned short* __restrict__ Ob) {  // [B,T,512] bf16 (concat heads)
  __shared__ unsigned short Ks[16384];       // [256][64], chunk^=(row&7)
  __shared__ unsigned short Vs[16384];       // [64][256], chunk^=((row&7)<<2)
  __shared__ unsigned short Ps[8][16][264];  // per-wave P rows
  int bh = blockIdx.x;
  int tid = threadIdx.x, wid = tid >> 6, lane = tid & 63, lr = lane & 15, lg = lane >> 4;
  int bb = bh >> 3, h = bh & 7;
  const unsigned short* Kg = Kb + (size_t)bh * 16384;
  const unsigned short* Vg = Vtb + (size_t)bh * 16384;
#pragma unroll
  for (int c = 0; c < 4; ++c) {
    int d = (wid * 4 + c) * 64 + lane;
    int kr = d >> 3, kc = (d & 7) ^ (kr & 7);
    async16(Kg + (size_t)kr * 64 + kc * 8, Ks + (wid * 4 + c) * 512);
    int vr = d >> 5, vc = (d & 31) ^ ((vr & 7) << 2);
    async16(Vg + (size_t)vr * 256 + vc * 8, Vs + (wid * 4 + c) * 512);
  }
  __syncthreads();   // vmcnt(0) drain + barrier

#pragma unroll
  for (int cc = 0; cc < 2; ++cc) {
    int ci = cc ? (15 - wid) : wid;
    int t0 = ci * 16, trow = t0 + lr;
    int ntV = ci + 1;
    int ntE = (ntV + 1) & ~1;
    int nk32 = ntE >> 1;
    const unsigned short* qsrc = Qb + (size_t)bh * 16384 + (size_t)(t0 + lr) * 64 + lg * 8;
    bf16x8 bq0 = *(const bf16x8*)qsrc;
    bf16x8 bq1 = *(const bf16x8*)(qsrc + 32);
    f32x4 acc[16];
#pragma unroll
    for (int nt = 0; nt < 16; ++nt)
      if (nt < ntE) acc[nt] = (f32x4){0.f, 0.f, 0.f, 0.f};
#pragma unroll
    for (int nt = 0; nt < 16; ++nt)
      if (nt < ntV) {
        int row = nt * 16 + lr;
        bf16x8 ak0 = *(const bf16x8*)&Ks[row * 64 + ((0 + lg) ^ (lr & 7)) * 8];
        acc[nt] = __builtin_amdgcn_mfma_f32_16x16x32_bf16(ak0, bq0, acc[nt], 0, 0, 0);
        bf16x8 ak1 = *(const bf16x8*)&Ks[row * 64 + ((4 + lg) ^ (lr & 7)) * 8];
        acc[nt] = __builtin_amdgcn_mfma_f32_16x16x32_bf16(ak1, bq1, acc[nt], 0, 0, 0);
      }
    float m = -3.0e38f;
#pragma unroll
    for (int nt = 0; nt < 16; ++nt)
      if (nt < ntE) {
#pragma unroll
        for (int r = 0; r < 4; ++r) {
          float v = acc[nt][r] * 0.125f;
          if (nt * 16 + lg * 4 + r > trow) v = -1.0e30f;
          acc[nt][r] = v;
          m = fmaxf(m, v);
        }
      }
    m = fmaxf(m, __shfl_xor(m, 16));
    m = fmaxf(m, __shfl_xor(m, 32));
    float s = 0.f;
#pragma unroll
    for (int nt = 0; nt < 16; ++nt)
      if (nt < ntE) {
        bf16x4 pk;
#pragma unroll
        for (int r = 0; r < 4; ++r) {
          float p = __expf(acc[nt][r] - m);
          s += p;
          pk[r] = (__bf16)p;
        }
        *(bf16x4*)&Ps[wid][lr][nt * 16 + lg * 4] = pk;
      }
    s += __shfl_xor(s, 16);
    s += __shfl_xor(s, 32);
    float inv = 1.0f / s;
    __threadfence_block();
    f32x4 aco[4];
#pragma unroll
    for (int vt = 0; vt < 4; ++vt) aco[vt] = (f32x4){0.f, 0.f, 0.f, 0.f};
#pragma unroll
    for (int k32 = 0; k32 < 8; ++k32)
      if (k32 < nk32) {
        bf16x8 pb = *(const bf16x8*)&Ps[wid][lr][k32 * 32 + lg * 8];
#pragma unroll
        for (int vt = 0; vt < 4; ++vt) {
          int row = vt * 16 + lr;
          bf16x8 av = *(const bf16x8*)&Vs[row * 256 + (((k32 * 4 + lg) ^ ((lr & 7) << 2)) * 8)];
          aco[vt] = __builtin_amdgcn_mfma_f32_16x16x32_bf16(av, pb, aco[vt], 0, 0, 0);
        }
      }
    unsigned short* obase = Ob + (size_t)(bb * 256 + trow) * 512 + h * 64 + lg * 4;
#pragma unroll
    for (int vt = 0; vt < 4; ++vt) {
      bf16x4 ov;
#pragma unroll
      for (int r = 0; r < 4; ++r) ov[r] = (__bf16)(aco[vt][r] * inv);
      *(bf16x4*)(obase + vt * 16) = ov;
    }
    __threadfence_block();
  }
}

extern "C" void kernel_launch(void* const* d_in, const int* in_sizes, int n_in,
                              void* d_out, int out_size, void* d_ws, size_t ws_size,
                              hipStream_t stream) {
  (void)in_sizes; (void)n_in; (void)out_size; (void)ws_size;
  const float* x = (const float*)d_in[0];
  const float* Wq = (const float*)d_in[1];
  const float* Wk = (const float*)d_in[2];
  const float* Wv = (const float*)d_in[3];
  const float* Wo = (const float*)d_in[4];
  const float* bo = (const float*)d_in[5];
  float* out = (float*)d_out;
  char* ws = (char*)d_ws;
  const size_t MB = 1024 * 1024;
  unsigned short* Qb = (unsigned short*)(ws);             // 32 MB
  unsigned short* Kb = (unsigned short*)(ws + 32 * MB);   // 32 MB
  unsigned short* Vtb = (unsigned short*)(ws + 64 * MB);  // 32 MB
  unsigned short* xb = (unsigned short*)(ws + 96 * MB);   // 32 MB (reused as attn out)
  unsigned short* Wqt = (unsigned short*)(ws + 128 * MB); // [512][512]; Wkt follows -> [1024][512]
  unsigned short* Wkt = Wqt + 262144;
  unsigned short* Wvt = Wkt + 262144;
  unsigned short* Wot = Wvt + 262144;

  hipLaunchKernelGGL(k_convert_x, dim3(8192), dim3(256), 0, stream, x, xb);
  hipLaunchKernelGGL(k_transpose_w3, dim3(1, 8, 24), dim3(256), 0, stream, Wq, Wk, Wv, Wqt);
  hipLaunchKernelGGL(k_transpose_w, dim3(8, 8, 1), dim3(256), 0, stream, Wo, Wot, 512, 512);
  // QK projection: B = [Wqt;Wkt] = [1024][512]
  hipLaunchKernelGGL((k_gemmP<0>), dim3(512), dim3(512), 0, stream,
                     xb, Wqt, Qb, Kb, (const float*)nullptr, (float*)nullptr);
  // V projection -> V^T
  hipLaunchKernelGGL((k_gemmP<2>), dim3(256), dim3(512), 0, stream,
                     xb, Wvt, Vtb, (unsigned short*)nullptr, (const float*)nullptr, (float*)nullptr);
  hipLaunchKernelGGL(k_attn2, dim3(1024), dim3(512), 0, stream, Qb, Kb, Vtb, xb);
  hipLaunchKernelGGL((k_gemmP<1>), dim3(256), dim3(512), 0, stream,
                     xb, Wot, (unsigned short*)nullptr, (unsigned short*)nullptr, bo, out);
}

// Round 9
// 169.908 us; speedup vs baseline: 1.0827x; 1.0827x over previous
//
#include <hip/hip_runtime.h>
#include <hip/hip_bf16.h>

typedef __bf16 bf16x8 __attribute__((ext_vector_type(8)));
typedef __bf16 bf16x4 __attribute__((ext_vector_type(4)));
typedef float f32x4 __attribute__((ext_vector_type(4)));
typedef unsigned short u16x8 __attribute__((ext_vector_type(8)));

// B=128, T=256, D=512, H=8, HD=64. M = B*T = 32768.

__device__ __forceinline__ unsigned short f2bf(float f) {
  unsigned u = __float_as_uint(f);
  u += 0x7fffu + ((u >> 16) & 1u);   // RNE
  return (unsigned short)(u >> 16);
}

__device__ __forceinline__ bf16x4 cvt4(f32x4 v) {
  bf16x4 o;
  o[0] = (__bf16)v[0]; o[1] = (__bf16)v[1]; o[2] = (__bf16)v[2]; o[3] = (__bf16)v[3];
  return o;
}

// async global->LDS, 16B per lane. LDS dest wave-uniform; HW adds lane*16.
__device__ __forceinline__ void async16(const void* g, void* l) {
  __builtin_amdgcn_global_load_lds(
      (const __attribute__((address_space(1))) void*)g,
      (__attribute__((address_space(3))) void*)l, 16, 0, 0);
}

// ---------------- x fp32 -> bf16 ----------------
__global__ __launch_bounds__(256) void k_convert_x(const float* __restrict__ in,
                                                   unsigned short* __restrict__ out) {
  int i = blockIdx.x * 256 + threadIdx.x;
  const float4* p = (const float4*)in + (size_t)i * 2;
  float4 a = p[0], b = p[1];
  u16x8 o;
  o[0] = f2bf(a.x); o[1] = f2bf(a.y); o[2] = f2bf(a.z); o[3] = f2bf(a.w);
  o[4] = f2bf(b.x); o[5] = f2bf(b.y); o[6] = f2bf(b.z); o[7] = f2bf(b.w);
  *((u16x8*)out + i) = o;
}

// ---------------- Wq/Wk/Wv fp32 [512][64] -> bf16 [64][512], 3 weights in one launch ----------------
__global__ __launch_bounds__(256) void k_transpose_w3(const float* __restrict__ w0,
                                                      const float* __restrict__ w1,
                                                      const float* __restrict__ w2,
                                                      unsigned short* __restrict__ out) {
  __shared__ unsigned short tile[64][72];
  int z = blockIdx.z;
  int wsel = z >> 3, hsel = z & 7;
  const float* inb = (wsel == 0 ? w0 : (wsel == 1 ? w1 : w2)) + (size_t)hsel * 512 * 64;
  unsigned short* outb = out + (size_t)z * 512 * 64;
  int r0 = blockIdx.y * 64;
  int tid = threadIdx.x;
  int r = tid >> 2, cq = (tid & 3) * 16;
  const float* src = inb + (size_t)(r0 + r) * 64 + cq;
#pragma unroll
  for (int i = 0; i < 16; i += 4) {
    float4 v = *(const float4*)(src + i);
    tile[r][cq + i + 0] = f2bf(v.x);
    tile[r][cq + i + 1] = f2bf(v.y);
    tile[r][cq + i + 2] = f2bf(v.z);
    tile[r][cq + i + 3] = f2bf(v.w);
  }
  __syncthreads();
  int cr = tid >> 2, rq = (tid & 3) * 16;
  u16x8 o0, o1;
#pragma unroll
  for (int i = 0; i < 8; ++i) o0[i] = tile[rq + i][cr];
#pragma unroll
  for (int i = 0; i < 8; ++i) o1[i] = tile[rq + 8 + i][cr];
  unsigned short* dst = outb + (size_t)cr * 512 + r0 + rq;
  *(u16x8*)dst = o0;
  *(u16x8*)(dst + 8) = o1;
}

// ---------------- Wo fp32 [512][512] -> bf16 [512][512]^T ----------------
__global__ __launch_bounds__(256) void k_transpose_w(const float* __restrict__ in,
                                                     unsigned short* __restrict__ out,
                                                     int rows, int cols) {
  __shared__ unsigned short tile[64][72];
  int c0 = blockIdx.x * 64, r0 = blockIdx.y * 64;
  int tid = threadIdx.x;
  int r = tid >> 2, cq = (tid & 3) * 16;
  const float* src = in + (size_t)(r0 + r) * cols + c0 + cq;
#pragma unroll
  for (int i = 0; i < 16; i += 4) {
    float4 v = *(const float4*)(src + i);
    tile[r][cq + i + 0] = f2bf(v.x);
    tile[r][cq + i + 1] = f2bf(v.y);
    tile[r][cq + i + 2] = f2bf(v.z);
    tile[r][cq + i + 3] = f2bf(v.w);
  }
  __syncthreads();
  int cr = tid >> 2, rq = (tid & 3) * 16;
  u16x8 o0, o1;
#pragma unroll
  for (int i = 0; i < 8; ++i) o0[i] = tile[rq + i][cr];
#pragma unroll
  for (int i = 0; i < 8; ++i) o1[i] = tile[rq + 8 + i][cr];
  unsigned short* dst = out + (size_t)(c0 + cr) * rows + r0 + rq;
  *(u16x8*)dst = o0;
  *(u16x8*)(dst + 8) = o1;
}

// ---------------- 256x256x(K=512) GEMM, m201-style 4-phase/K-tile ----------------
// Fragment row maps are half-aligned: A row = mi*32+wm*16+lr (a03->A0, a47->A1),
// B row = ni*64+wn*16+lr (b01->B0, b23->B1). Per phase: {subtile ds_reads + stage ONE
// half of tile t+1 (2 async16, into the INACTIVE buffer -> no WAR) -> barrier ->
// lgkm(0) -> setprio+16 MFMA -> vmcnt(4) -> barrier}. Counted vmcnt keeps 2 half-tiles
// in flight; every staged half has >=3 phases to land. Tail tile: vmcnt(2)/vmcnt(0).
// KIND 0: x*Wqk^T -> Q,K [B,H,T,HD] (swapped mfma: packed hd stores). grid 512.
// KIND 1: a*Wo^T + bo -> fp32 out (swapped mfma: packed float4 stores). grid 256.
// KIND 2: x*Wv^T -> V^T [B,H,HD,T] (normal mfma: packed t stores).     grid 256.
template <int KIND>
__global__ __launch_bounds__(512, 1) void k_gemmP(
    const unsigned short* __restrict__ A,
    const unsigned short* __restrict__ Bmat,
    unsigned short* __restrict__ O0,
    unsigned short* __restrict__ O1,
    const float* __restrict__ bo,
    float* __restrict__ outf) {
  __shared__ unsigned short smem[65536];   // 2 bufs x (A[256][64] | B[256][64])
  const int P = (KIND == 0) ? 64 : 32;     // blocks per XCD
  int xcd = blockIdx.x & 7, g = blockIdx.x >> 3;
  int w = xcd * P + g;
  int mt, nt;
  if (KIND == 0) { mt = w >> 2; nt = w & 3; }
  else           { mt = w >> 1; nt = w & 1; }
  int m0 = mt * 256, n0 = nt * 256;
  int tid = threadIdx.x;
  int wid = tid >> 6, lane = tid & 63;
  int lr = lane & 15, lg = lane >> 4;
  int wm = wid >> 2, wn = wid & 3;

  int srow_off = wid * 16 + (lane >> 3);
  int schunk = (lane & 7) ^ (lane >> 3);   // inverse-swizzled source chunk (rule 21)
  auto stageA = [&](int kb, int buf, int half) {
#pragma unroll
    for (int j = 0; j < 2; ++j) {
      int row = half * 128 + srow_off + j * 8;
      async16(A + (size_t)(m0 + row) * 512 + kb * 64 + schunk * 8,
              smem + buf * 32768 + half * 8192 + (wid * 2 + j) * 512);
    }
  };
  auto stageB = [&](int kb, int buf, int half) {
#pragma unroll
    for (int j = 0; j < 2; ++j) {
      int row = half * 128 + srow_off + j * 8;
      async16(Bmat + (size_t)(n0 + row) * 512 + kb * 64 + schunk * 8,
              smem + buf * 32768 + 16384 + half * 8192 + (wid * 2 + j) * 512);
    }
  };
  auto lda = [&](int buf, int mi, int k32) -> bf16x8 {
    int row = mi * 32 + wm * 16 + lr;
    int ch = (k32 * 4 + lg) ^ (lr & 7);
    return *(const bf16x8*)&smem[buf * 32768 + row * 64 + ch * 8];
  };
  auto ldb = [&](int buf, int ni, int k32) -> bf16x8 {
    int row = ni * 64 + wn * 16 + lr;
    int ch = (k32 * 4 + lg) ^ (lr & 7);
    return *(const bf16x8*)&smem[buf * 32768 + 16384 + row * 64 + ch * 8];
  };

  f32x4 acc[8][4];
#pragma unroll
  for (int mi = 0; mi < 8; ++mi)
#pragma unroll
    for (int ni = 0; ni < 4; ++ni) acc[mi][ni] = (f32x4){0.f, 0.f, 0.f, 0.f};

#define MF(dst, afrag, bfrag)                                                        \
  if constexpr (KIND == 2)                                                           \
    dst = __builtin_amdgcn_mfma_f32_16x16x32_bf16(afrag, bfrag, dst, 0, 0, 0);       \
  else                                                                               \
    dst = __builtin_amdgcn_mfma_f32_16x16x32_bf16(bfrag, afrag, dst, 0, 0, 0);
#define BAR_LGKM()                                      \
  __builtin_amdgcn_s_barrier();                         \
  asm volatile("s_waitcnt lgkmcnt(0)" ::: "memory");

  // prologue: tile0 halves in order [A0,B0,A1,B1]; wait A0,B0 (leave 4 in flight)
  stageA(0, 0, 0); stageB(0, 0, 0); stageA(0, 0, 1); stageB(0, 0, 1);
  asm volatile("s_waitcnt vmcnt(4)" ::: "memory");
  __builtin_amdgcn_s_barrier();
  asm volatile("" ::: "memory");

  bf16x8 a03[4][2], a47[4][2], b01[2][2], b23[2][2];
#pragma unroll
  for (int t = 0; t < 8; ++t) {
    int buf = t & 1, nbuf = buf ^ 1;
    const bool st = (t < 7);
    // ---- phase 1: reads A0-sub (a03) + B0-sub (b01); stage A0(t+1); MFMA Q00 ----
#pragma unroll
    for (int mi = 0; mi < 4; ++mi) { a03[mi][0] = lda(buf, mi, 0); a03[mi][1] = lda(buf, mi, 1); }
#pragma unroll
    for (int ni = 0; ni < 2; ++ni) { b01[ni][0] = ldb(buf, ni, 0); b01[ni][1] = ldb(buf, ni, 1); }
    if (st) stageA(t + 1, nbuf, 0);
    BAR_LGKM();
    __builtin_amdgcn_s_setprio(1);
#pragma unroll
    for (int mi = 0; mi < 4; ++mi)
#pragma unroll
      for (int ni = 0; ni < 2; ++ni)
#pragma unroll
        for (int k = 0; k < 2; ++k) { MF(acc[mi][ni], a03[mi][k], b01[ni][k]); }
    __builtin_amdgcn_s_setprio(0);
    if (st) asm volatile("s_waitcnt vmcnt(4)" ::: "memory");
    else    asm volatile("s_waitcnt vmcnt(2)" ::: "memory");
    __builtin_amdgcn_s_barrier();
    asm volatile("" ::: "memory");
    // ---- phase 2: reads A1-sub (a47); stage B0(t+1); MFMA Q10 ----
#pragma unroll
    for (int mi = 0; mi < 4; ++mi) { a47[mi][0] = lda(buf, mi + 4, 0); a47[mi][1] = lda(buf, mi + 4, 1); }
    if (st) stageB(t + 1, nbuf, 0);
    BAR_LGKM();
    __builtin_amdgcn_s_setprio(1);
#pragma unroll
    for (int mi = 0; mi < 4; ++mi)
#pragma unroll
      for (int ni = 0; ni < 2; ++ni)
#pragma unroll
        for (int k = 0; k < 2; ++k) { MF(acc[mi + 4][ni], a47[mi][k], b01[ni][k]); }
    __builtin_amdgcn_s_setprio(0);
    if (st) asm volatile("s_waitcnt vmcnt(4)" ::: "memory");
    else    asm volatile("s_waitcnt vmcnt(0)" ::: "memory");
    __builtin_amdgcn_s_barrier();
    asm volatile("" ::: "memory");
    // ---- phase 3: reads B1-sub (b23); stage A1(t+1); MFMA Q11 ----
#pragma unroll
    for (int ni = 0; ni < 2; ++ni) { b23[ni][0] = ldb(buf, ni + 2, 0); b23[ni][1] = ldb(buf, ni + 2, 1); }
    if (st) stageA(t + 1, nbuf, 1);
    BAR_LGKM();
    __builtin_amdgcn_s_setprio(1);
#pragma unroll
    for (int mi = 0; mi < 4; ++mi)
#pragma unroll
      for (int ni = 0; ni < 2; ++ni)
#pragma unroll
        for (int k = 0; k < 2; ++k) { MF(acc[mi + 4][ni + 2], a47[mi][k], b23[ni][k]); }
    __builtin_amdgcn_s_setprio(0);
    if (st) asm volatile("s_waitcnt vmcnt(4)" ::: "memory");
    __builtin_amdgcn_s_barrier();
    asm volatile("" ::: "memory");
    // ---- phase 4: stage B1(t+1); MFMA Q01 ----
    if (st) stageB(t + 1, nbuf, 1);
    __builtin_amdgcn_s_barrier();
    __builtin_amdgcn_s_setprio(1);
#pragma unroll
    for (int mi = 0; mi < 4; ++mi)
#pragma unroll
      for (int ni = 0; ni < 2; ++ni)
#pragma unroll
        for (int k = 0; k < 2; ++k) { MF(acc[mi][ni + 2], a03[mi][k], b23[ni][k]); }
    __builtin_amdgcn_s_setprio(0);
    if (st) asm volatile("s_waitcnt vmcnt(4)" ::: "memory");
    __builtin_amdgcn_s_barrier();
    asm volatile("" ::: "memory");
  }
#undef MF
#undef BAR_LGKM

  // ---- epilogues (write straight from acc; no LDS use) ----
  // swapped kinds: acc[mi][ni][r] = C[m = mi*32+wm*16+lr][n = ni*64+wn*16+lg*4+r]
  // normal  kind:  acc[mi][ni][r] = C[m = mi*32+wm*16+lg*4+r][n = ni*64+wn*16+lr]
  if constexpr (KIND == 0) {
    int z = n0 >> 9;
    int hbase = (n0 & 511) >> 6;
    int hd0 = wn * 16 + lg * 4;
#pragma unroll
    for (int ni = 0; ni < 4; ++ni) {
      unsigned short* outp = (z ? O1 : O0) + (size_t)(mt * 8 + hbase + ni) * 16384;
#pragma unroll
      for (int mi = 0; mi < 8; ++mi) {
        int tq = mi * 32 + wm * 16 + lr;
        *(bf16x4*)&outp[(size_t)tq * 64 + hd0] = cvt4(acc[mi][ni]);
      }
    }
  } else if constexpr (KIND == 1) {
#pragma unroll
    for (int ni = 0; ni < 4; ++ni) {
      int nb = n0 + ni * 64 + wn * 16 + lg * 4;
      float4 b4 = *(const float4*)&bo[nb];
#pragma unroll
      for (int mi = 0; mi < 8; ++mi) {
        int mg = m0 + mi * 32 + wm * 16 + lr;
        float4 o;
        o.x = acc[mi][ni][0] + b4.x; o.y = acc[mi][ni][1] + b4.y;
        o.z = acc[mi][ni][2] + b4.z; o.w = acc[mi][ni][3] + b4.w;
        *(float4*)&outf[(size_t)mg * 512 + nb] = o;
      }
    }
  } else {
    int hbase = n0 >> 6;
    int hd = wn * 16 + lr;
#pragma unroll
    for (int ni = 0; ni < 4; ++ni) {
      unsigned short* outp = O0 + (size_t)(mt * 8 + hbase + ni) * 16384;
#pragma unroll
      for (int mi = 0; mi < 8; ++mi) {
        int tq = mi * 32 + wm * 16 + lg * 4;
        *(bf16x4*)&outp[(size_t)hd * 256 + tq] = cvt4(acc[mi][ni]);
      }
    }
  }
}

// ---------------- fused causal attention v2: LDS K/V, balanced chunk pairs ----------------
__global__ __launch_bounds__(512, 1) void k_attn2(
    const unsigned short* __restrict__ Qb,
    const unsigned short* __restrict__ Kb,
    const unsigned short* __restrict__ Vtb,
    unsigned short* __restrict__ Ob) {  // [B,T,512] bf16 (concat heads)
  __shared__ unsigned short Ks[16384];       // [256][64], chunk^=(row&7)
  __shared__ unsigned short Vs[16384];       // [64][256], chunk^=((row&7)<<2)
  __shared__ unsigned short Ps[8][16][264];  // per-wave P rows
  int bh = blockIdx.x;
  int tid = threadIdx.x, wid = tid >> 6, lane = tid & 63, lr = lane & 15, lg = lane >> 4;
  int bb = bh >> 3, h = bh & 7;
  const unsigned short* Kg = Kb + (size_t)bh * 16384;
  const unsigned short* Vg = Vtb + (size_t)bh * 16384;
#pragma unroll
  for (int c = 0; c < 4; ++c) {
    int d = (wid * 4 + c) * 64 + lane;
    int kr = d >> 3, kc = (d & 7) ^ (kr & 7);
    async16(Kg + (size_t)kr * 64 + kc * 8, Ks + (wid * 4 + c) * 512);
    int vr = d >> 5, vc = (d & 31) ^ ((vr & 7) << 2);
    async16(Vg + (size_t)vr * 256 + vc * 8, Vs + (wid * 4 + c) * 512);
  }
  __syncthreads();   // vmcnt(0) drain + barrier

#pragma unroll
  for (int cc = 0; cc < 2; ++cc) {
    int ci = cc ? (15 - wid) : wid;
    int t0 = ci * 16, trow = t0 + lr;
    int ntV = ci + 1;
    int ntE = (ntV + 1) & ~1;
    int nk32 = ntE >> 1;
    const unsigned short* qsrc = Qb + (size_t)bh * 16384 + (size_t)(t0 + lr) * 64 + lg * 8;
    bf16x8 bq0 = *(const bf16x8*)qsrc;
    bf16x8 bq1 = *(const bf16x8*)(qsrc + 32);
    f32x4 acc[16];
#pragma unroll
    for (int nt = 0; nt < 16; ++nt)
      if (nt < ntE) acc[nt] = (f32x4){0.f, 0.f, 0.f, 0.f};
#pragma unroll
    for (int nt = 0; nt < 16; ++nt)
      if (nt < ntV) {
        int row = nt * 16 + lr;
        bf16x8 ak0 = *(const bf16x8*)&Ks[row * 64 + ((0 + lg) ^ (lr & 7)) * 8];
        acc[nt] = __builtin_amdgcn_mfma_f32_16x16x32_bf16(ak0, bq0, acc[nt], 0, 0, 0);
        bf16x8 ak1 = *(const bf16x8*)&Ks[row * 64 + ((4 + lg) ^ (lr & 7)) * 8];
        acc[nt] = __builtin_amdgcn_mfma_f32_16x16x32_bf16(ak1, bq1, acc[nt], 0, 0, 0);
      }
    float m = -3.0e38f;
#pragma unroll
    for (int nt = 0; nt < 16; ++nt)
      if (nt < ntE) {
#pragma unroll
        for (int r = 0; r < 4; ++r) {
          float v = acc[nt][r] * 0.125f;
          if (nt * 16 + lg * 4 + r > trow) v = -1.0e30f;
          acc[nt][r] = v;
          m = fmaxf(m, v);
        }
      }
    m = fmaxf(m, __shfl_xor(m, 16));
    m = fmaxf(m, __shfl_xor(m, 32));
    float s = 0.f;
#pragma unroll
    for (int nt = 0; nt < 16; ++nt)
      if (nt < ntE) {
        bf16x4 pk;
#pragma unroll
        for (int r = 0; r < 4; ++r) {
          float p = __expf(acc[nt][r] - m);
          s += p;
          pk[r] = (__bf16)p;
        }
        *(bf16x4*)&Ps[wid][lr][nt * 16 + lg * 4] = pk;
      }
    s += __shfl_xor(s, 16);
    s += __shfl_xor(s, 32);
    float inv = 1.0f / s;
    __threadfence_block();
    f32x4 aco[4];
#pragma unroll
    for (int vt = 0; vt < 4; ++vt) aco[vt] = (f32x4){0.f, 0.f, 0.f, 0.f};
#pragma unroll
    for (int k32 = 0; k32 < 8; ++k32)
      if (k32 < nk32) {
        bf16x8 pb = *(const bf16x8*)&Ps[wid][lr][k32 * 32 + lg * 8];
#pragma unroll
        for (int vt = 0; vt < 4; ++vt) {
          int row = vt * 16 + lr;
          bf16x8 av = *(const bf16x8*)&Vs[row * 256 + (((k32 * 4 + lg) ^ ((lr & 7) << 2)) * 8)];
          aco[vt] = __builtin_amdgcn_mfma_f32_16x16x32_bf16(av, pb, aco[vt], 0, 0, 0);
        }
      }
    unsigned short* obase = Ob + (size_t)(bb * 256 + trow) * 512 + h * 64 + lg * 4;
#pragma unroll
    for (int vt = 0; vt < 4; ++vt) {
      bf16x4 ov;
#pragma unroll
      for (int r = 0; r < 4; ++r) ov[r] = (__bf16)(aco[vt][r] * inv);
      *(bf16x4*)(obase + vt * 16) = ov;
    }
    __threadfence_block();
  }
}

extern "C" void kernel_launch(void* const* d_in, const int* in_sizes, int n_in,
                              void* d_out, int out_size, void* d_ws, size_t ws_size,
                              hipStream_t stream) {
  (void)in_sizes; (void)n_in; (void)out_size; (void)ws_size;
  const float* x = (const float*)d_in[0];
  const float* Wq = (const float*)d_in[1];
  const float* Wk = (const float*)d_in[2];
  const float* Wv = (const float*)d_in[3];
  const float* Wo = (const float*)d_in[4];
  const float* bo = (const float*)d_in[5];
  float* out = (float*)d_out;
  char* ws = (char*)d_ws;
  const size_t MB = 1024 * 1024;
  unsigned short* Qb = (unsigned short*)(ws);             // 32 MB
  unsigned short* Kb = (unsigned short*)(ws + 32 * MB);   // 32 MB
  unsigned short* Vtb = (unsigned short*)(ws + 64 * MB);  // 32 MB
  unsigned short* xb = (unsigned short*)(ws + 96 * MB);   // 32 MB (reused as attn out)
  unsigned short* Wqt = (unsigned short*)(ws + 128 * MB); // [512][512]; Wkt follows -> [1024][512]
  unsigned short* Wkt = Wqt + 262144;
  unsigned short* Wvt = Wkt + 262144;
  unsigned short* Wot = Wvt + 262144;

  hipLaunchKernelGGL(k_convert_x, dim3(8192), dim3(256), 0, stream, x, xb);
  hipLaunchKernelGGL(k_transpose_w3, dim3(1, 8, 24), dim3(256), 0, stream, Wq, Wk, Wv, Wqt);
  hipLaunchKernelGGL(k_transpose_w, dim3(8, 8, 1), dim3(256), 0, stream, Wo, Wot, 512, 512);
  // QK projection: B = [Wqt;Wkt] = [1024][512]
  hipLaunchKernelGGL((k_gemmP<0>), dim3(512), dim3(512), 0, stream,
                     xb, Wqt, Qb, Kb, (const float*)nullptr, (float*)nullptr);
  // V projection -> V^T
  hipLaunchKernelGGL((k_gemmP<2>), dim3(256), dim3(512), 0, stream,
                     xb, Wvt, Vtb, (unsigned short*)nullptr, (const float*)nullptr, (float*)nullptr);
  hipLaunchKernelGGL(k_attn2, dim3(1024), dim3(512), 0, stream, Qb, Kb, Vtb, xb);
  hipLaunchKernelGGL((k_gemmP<1>), dim3(256), dim3(512), 0, stream,
                     xb, Wot, (unsigned short*)nullptr, (unsigned short*)nullptr, bo, out);
}

// Round 10
// 168.337 us; speedup vs baseline: 1.0928x; 1.0093x over previous
//
#include <hip/hip_runtime.h>
#include <hip/hip_bf16.h>

typedef __bf16 bf16x8 __attribute__((ext_vector_type(8)));
typedef __bf16 bf16x4 __attribute__((ext_vector_type(4)));
typedef float f32x4 __attribute__((ext_vector_type(4)));
typedef unsigned short u16x8 __attribute__((ext_vector_type(8)));

// B=128, T=256, D=512, H=8, HD=64. M = B*T = 32768.

__device__ __forceinline__ unsigned short f2bf(float f) {
  unsigned u = __float_as_uint(f);
  u += 0x7fffu + ((u >> 16) & 1u);   // RNE
  return (unsigned short)(u >> 16);
}

__device__ __forceinline__ bf16x4 cvt4(f32x4 v) {
  bf16x4 o;
  o[0] = (__bf16)v[0]; o[1] = (__bf16)v[1]; o[2] = (__bf16)v[2]; o[3] = (__bf16)v[3];
  return o;
}

// async global->LDS, 16B per lane. LDS dest wave-uniform; HW adds lane*16.
__device__ __forceinline__ void async16(const void* g, void* l) {
  __builtin_amdgcn_global_load_lds(
      (const __attribute__((address_space(1))) void*)g,
      (__attribute__((address_space(3))) void*)l, 16, 0, 0);
}

// ---------------- x fp32 -> bf16 ----------------
__global__ __launch_bounds__(256) void k_convert_x(const float* __restrict__ in,
                                                   unsigned short* __restrict__ out) {
  int i = blockIdx.x * 256 + threadIdx.x;
  const float4* p = (const float4*)in + (size_t)i * 2;
  float4 a = p[0], b = p[1];
  u16x8 o;
  o[0] = f2bf(a.x); o[1] = f2bf(a.y); o[2] = f2bf(a.z); o[3] = f2bf(a.w);
  o[4] = f2bf(b.x); o[5] = f2bf(b.y); o[6] = f2bf(b.z); o[7] = f2bf(b.w);
  *((u16x8*)out + i) = o;
}

// ---------------- Wq/Wk/Wv fp32 [512][64] -> bf16 [64][512], 3 weights in one launch ----------------
__global__ __launch_bounds__(256) void k_transpose_w3(const float* __restrict__ w0,
                                                      const float* __restrict__ w1,
                                                      const float* __restrict__ w2,
                                                      unsigned short* __restrict__ out) {
  __shared__ unsigned short tile[64][72];
  int z = blockIdx.z;
  int wsel = z >> 3, hsel = z & 7;
  const float* inb = (wsel == 0 ? w0 : (wsel == 1 ? w1 : w2)) + (size_t)hsel * 512 * 64;
  unsigned short* outb = out + (size_t)z * 512 * 64;
  int r0 = blockIdx.y * 64;
  int tid = threadIdx.x;
  int r = tid >> 2, cq = (tid & 3) * 16;
  const float* src = inb + (size_t)(r0 + r) * 64 + cq;
#pragma unroll
  for (int i = 0; i < 16; i += 4) {
    float4 v = *(const float4*)(src + i);
    tile[r][cq + i + 0] = f2bf(v.x);
    tile[r][cq + i + 1] = f2bf(v.y);
    tile[r][cq + i + 2] = f2bf(v.z);
    tile[r][cq + i + 3] = f2bf(v.w);
  }
  __syncthreads();
  int cr = tid >> 2, rq = (tid & 3) * 16;
  u16x8 o0, o1;
#pragma unroll
  for (int i = 0; i < 8; ++i) o0[i] = tile[rq + i][cr];
#pragma unroll
  for (int i = 0; i < 8; ++i) o1[i] = tile[rq + 8 + i][cr];
  unsigned short* dst = outb + (size_t)cr * 512 + r0 + rq;
  *(u16x8*)dst = o0;
  *(u16x8*)(dst + 8) = o1;
}

// ---------------- Wo fp32 [512][512] -> bf16 [512][512]^T ----------------
__global__ __launch_bounds__(256) void k_transpose_w(const float* __restrict__ in,
                                                     unsigned short* __restrict__ out,
                                                     int rows, int cols) {
  __shared__ unsigned short tile[64][72];
  int c0 = blockIdx.x * 64, r0 = blockIdx.y * 64;
  int tid = threadIdx.x;
  int r = tid >> 2, cq = (tid & 3) * 16;
  const float* src = in + (size_t)(r0 + r) * cols + c0 + cq;
#pragma unroll
  for (int i = 0; i < 16; i += 4) {
    float4 v = *(const float4*)(src + i);
    tile[r][cq + i + 0] = f2bf(v.x);
    tile[r][cq + i + 1] = f2bf(v.y);
    tile[r][cq + i + 2] = f2bf(v.z);
    tile[r][cq + i + 3] = f2bf(v.w);
  }
  __syncthreads();
  int cr = tid >> 2, rq = (tid & 3) * 16;
  u16x8 o0, o1;
#pragma unroll
  for (int i = 0; i < 8; ++i) o0[i] = tile[rq + i][cr];
#pragma unroll
  for (int i = 0; i < 8; ++i) o1[i] = tile[rq + 8 + i][cr];
  unsigned short* dst = out + (size_t)(c0 + cr) * rows + r0 + rq;
  *(u16x8*)dst = o0;
  *(u16x8*)(dst + 8) = o1;
}

// ---------------- 256x256x(K=512) GEMM, 4-phase, minimal sync ----------------
// Per phase: {subtile ds_reads; stage ONE half of t+1 into inactive buffer;
// setprio+16 MFMA; [vmcnt(4) per FIFO deadline]; barrier}. 4 barriers + 3 vmcnt per
// tile (vs R8's 8+4): ph1/ph2/ph4 wait vmcnt(4), ph3 waitless. Compiler inserts
// fine-grained lgkmcnt for ds_read->MFMA deps; cross-wave staging visibility comes
// from each wave's own vmcnt + the phase barrier.
// KIND 0: x*Wqk^T -> Q,K [B,H,T,HD] (swapped mfma: packed hd stores). grid 512.
// KIND 1: a*Wo^T + bo -> fp32 out (swapped mfma: packed float4 stores). grid 256.
// KIND 2: x*Wv^T -> V^T [B,H,HD,T] (normal mfma: packed t stores).     grid 256.
template <int KIND>
__global__ __launch_bounds__(512, 1) void k_gemmP(
    const unsigned short* __restrict__ A,
    const unsigned short* __restrict__ Bmat,
    unsigned short* __restrict__ O0,
    unsigned short* __restrict__ O1,
    const float* __restrict__ bo,
    float* __restrict__ outf) {
  __shared__ unsigned short smem[65536];   // 2 bufs x (A[256][64] | B[256][64])
  const int P = (KIND == 0) ? 64 : 32;     // blocks per XCD
  int xcd = blockIdx.x & 7, g = blockIdx.x >> 3;
  int w = xcd * P + g;
  int mt, nt;
  if (KIND == 0) { mt = w >> 2; nt = w & 3; }
  else           { mt = w >> 1; nt = w & 1; }
  int m0 = mt * 256, n0 = nt * 256;
  int tid = threadIdx.x;
  int wid = tid >> 6, lane = tid & 63;
  int lr = lane & 15, lg = lane >> 4;
  int wm = wid >> 2, wn = wid & 3;

  int srow_off = wid * 16 + (lane >> 3);
  int schunk = (lane & 7) ^ (lane >> 3);   // inverse-swizzled source chunk (rule 21)
  auto stageA = [&](int kb, int buf, int half) {
#pragma unroll
    for (int j = 0; j < 2; ++j) {
      int row = half * 128 + srow_off + j * 8;
      async16(A + (size_t)(m0 + row) * 512 + kb * 64 + schunk * 8,
              smem + buf * 32768 + half * 8192 + (wid * 2 + j) * 512);
    }
  };
  auto stageB = [&](int kb, int buf, int half) {
#pragma unroll
    for (int j = 0; j < 2; ++j) {
      int row = half * 128 + srow_off + j * 8;
      async16(Bmat + (size_t)(n0 + row) * 512 + kb * 64 + schunk * 8,
              smem + buf * 32768 + 16384 + half * 8192 + (wid * 2 + j) * 512);
    }
  };
  auto lda = [&](int buf, int mi, int k32) -> bf16x8 {
    int row = mi * 32 + wm * 16 + lr;
    int ch = (k32 * 4 + lg) ^ (lr & 7);
    return *(const bf16x8*)&smem[buf * 32768 + row * 64 + ch * 8];
  };
  auto ldb = [&](int buf, int ni, int k32) -> bf16x8 {
    int row = ni * 64 + wn * 16 + lr;
    int ch = (k32 * 4 + lg) ^ (lr & 7);
    return *(const bf16x8*)&smem[buf * 32768 + 16384 + row * 64 + ch * 8];
  };

  f32x4 acc[8][4];
#pragma unroll
  for (int mi = 0; mi < 8; ++mi)
#pragma unroll
    for (int ni = 0; ni < 4; ++ni) acc[mi][ni] = (f32x4){0.f, 0.f, 0.f, 0.f};

#define MF(dst, afrag, bfrag)                                                        \
  if constexpr (KIND == 2)                                                           \
    dst = __builtin_amdgcn_mfma_f32_16x16x32_bf16(afrag, bfrag, dst, 0, 0, 0);       \
  else                                                                               \
    dst = __builtin_amdgcn_mfma_f32_16x16x32_bf16(bfrag, afrag, dst, 0, 0, 0);

  // prologue: tile0 halves [A0,B0,A1,B1]; wait A0,B0 (leave A1,B1 in flight)
  stageA(0, 0, 0); stageB(0, 0, 0); stageA(0, 0, 1); stageB(0, 0, 1);
  asm volatile("s_waitcnt vmcnt(4)" ::: "memory");
  __builtin_amdgcn_s_barrier();
  asm volatile("" ::: "memory");

  bf16x8 a03[4][2], a47[4][2], b01[2][2], b23[2][2];
#pragma unroll
  for (int t = 0; t < 8; ++t) {
    int buf = t & 1, nbuf = buf ^ 1;
    const bool st = (t < 7);
    // ---- phase 1: read a03(A0)+b01(B0); stage A0(t+1); MFMA Q00 ----
#pragma unroll
    for (int mi = 0; mi < 4; ++mi) { a03[mi][0] = lda(buf, mi, 0); a03[mi][1] = lda(buf, mi, 1); }
#pragma unroll
    for (int ni = 0; ni < 2; ++ni) { b01[ni][0] = ldb(buf, ni, 0); b01[ni][1] = ldb(buf, ni, 1); }
    if (st) stageA(t + 1, nbuf, 0);
    asm volatile("" ::: "memory");
    __builtin_amdgcn_s_setprio(1);
#pragma unroll
    for (int mi = 0; mi < 4; ++mi)
#pragma unroll
      for (int ni = 0; ni < 2; ++ni)
#pragma unroll
        for (int k = 0; k < 2; ++k) { MF(acc[mi][ni], a03[mi][k], b01[ni][k]); }
    __builtin_amdgcn_s_setprio(0);
    if (st) asm volatile("s_waitcnt vmcnt(4)" ::: "memory");   // drains A1(t) for ph2
    else    asm volatile("s_waitcnt vmcnt(2)" ::: "memory");
    __builtin_amdgcn_s_barrier();
    asm volatile("" ::: "memory");
    // ---- phase 2: read a47(A1); stage B0(t+1); MFMA Q10 ----
#pragma unroll
    for (int mi = 0; mi < 4; ++mi) { a47[mi][0] = lda(buf, mi + 4, 0); a47[mi][1] = lda(buf, mi + 4, 1); }
    if (st) stageB(t + 1, nbuf, 0);
    asm volatile("" ::: "memory");
    __builtin_amdgcn_s_setprio(1);
#pragma unroll
    for (int mi = 0; mi < 4; ++mi)
#pragma unroll
      for (int ni = 0; ni < 2; ++ni)
#pragma unroll
        for (int k = 0; k < 2; ++k) { MF(acc[mi + 4][ni], a47[mi][k], b01[ni][k]); }
    __builtin_amdgcn_s_setprio(0);
    if (st) asm volatile("s_waitcnt vmcnt(4)" ::: "memory");   // drains B1(t) for ph3
    else    asm volatile("s_waitcnt vmcnt(0)" ::: "memory");
    __builtin_amdgcn_s_barrier();
    asm volatile("" ::: "memory");
    // ---- phase 3: read b23(B1); stage A1(t+1); MFMA Q11; NO vmcnt ----
#pragma unroll
    for (int ni = 0; ni < 2; ++ni) { b23[ni][0] = ldb(buf, ni + 2, 0); b23[ni][1] = ldb(buf, ni + 2, 1); }
    if (st) stageA(t + 1, nbuf, 1);
    asm volatile("" ::: "memory");
    __builtin_amdgcn_s_setprio(1);
#pragma unroll
    for (int mi = 0; mi < 4; ++mi)
#pragma unroll
      for (int ni = 0; ni < 2; ++ni)
#pragma unroll
        for (int k = 0; k < 2; ++k) { MF(acc[mi + 4][ni + 2], a47[mi][k], b23[ni][k]); }
    __builtin_amdgcn_s_setprio(0);
    __builtin_amdgcn_s_barrier();
    asm volatile("" ::: "memory");
    // ---- phase 4: stage B1(t+1); MFMA Q01; vmcnt(4) (drains A0',B0' for next ph1) ----
    if (st) stageB(t + 1, nbuf, 1);
    asm volatile("" ::: "memory");
    __builtin_amdgcn_s_setprio(1);
#pragma unroll
    for (int mi = 0; mi < 4; ++mi)
#pragma unroll
      for (int ni = 0; ni < 2; ++ni)
#pragma unroll
        for (int k = 0; k < 2; ++k) { MF(acc[mi][ni + 2], a03[mi][k], b23[ni][k]); }
    __builtin_amdgcn_s_setprio(0);
    if (st) asm volatile("s_waitcnt vmcnt(4)" ::: "memory");
    __builtin_amdgcn_s_barrier();
    asm volatile("" ::: "memory");
  }
#undef MF

  // ---- epilogues (write straight from acc; no LDS use) ----
  // swapped kinds: acc[mi][ni][r] = C[m = mi*32+wm*16+lr][n = ni*64+wn*16+lg*4+r]
  // normal  kind:  acc[mi][ni][r] = C[m = mi*32+wm*16+lg*4+r][n = ni*64+wn*16+lr]
  if constexpr (KIND == 0) {
    int z = n0 >> 9;
    int hbase = (n0 & 511) >> 6;
    int hd0 = wn * 16 + lg * 4;
#pragma unroll
    for (int ni = 0; ni < 4; ++ni) {
      unsigned short* outp = (z ? O1 : O0) + (size_t)(mt * 8 + hbase + ni) * 16384;
#pragma unroll
      for (int mi = 0; mi < 8; ++mi) {
        int tq = mi * 32 + wm * 16 + lr;
        *(bf16x4*)&outp[(size_t)tq * 64 + hd0] = cvt4(acc[mi][ni]);
      }
    }
  } else if constexpr (KIND == 1) {
#pragma unroll
    for (int ni = 0; ni < 4; ++ni) {
      int nb = n0 + ni * 64 + wn * 16 + lg * 4;
      float4 b4 = *(const float4*)&bo[nb];
#pragma unroll
      for (int mi = 0; mi < 8; ++mi) {
        int mg = m0 + mi * 32 + wm * 16 + lr;
        float4 o;
        o.x = acc[mi][ni][0] + b4.x; o.y = acc[mi][ni][1] + b4.y;
        o.z = acc[mi][ni][2] + b4.z; o.w = acc[mi][ni][3] + b4.w;
        *(float4*)&outf[(size_t)mg * 512 + nb] = o;
      }
    }
  } else {
    int hbase = n0 >> 6;
    int hd = wn * 16 + lr;
#pragma unroll
    for (int ni = 0; ni < 4; ++ni) {
      unsigned short* outp = O0 + (size_t)(mt * 8 + hbase + ni) * 16384;
#pragma unroll
      for (int mi = 0; mi < 8; ++mi) {
        int tq = mi * 32 + wm * 16 + lg * 4;
        *(bf16x4*)&outp[(size_t)hd * 256 + tq] = cvt4(acc[mi][ni]);
      }
    }
  }
}

// ---------------- fused causal attention v3: streaming P slot -> 2 blocks/CU ----------------
// LDS = K 32K + V^T 32K + Ps 9K = 73 KiB -> 2 blocks/CU (16 waves). P kept packed in
// registers (pk[nt]); per k32 the per-wave slot [16][36] is read (current pair) then
// rewritten (next pair) -- same-wave LDS FIFO is in-order, so RAW/WAR are safe.
__global__ __launch_bounds__(512, 4) void k_attn2(
    const unsigned short* __restrict__ Qb,
    const unsigned short* __restrict__ Kb,
    const unsigned short* __restrict__ Vtb,
    unsigned short* __restrict__ Ob) {  // [B,T,512] bf16 (concat heads)
  __shared__ unsigned short Ks[16384];       // [256][64], chunk^=(row&7)
  __shared__ unsigned short Vs[16384];       // [64][256], chunk^=((row&7)<<2)
  __shared__ unsigned short Ps[8][16][36];   // per-wave 32-value slot (stride 72B)
  int bh = blockIdx.x;
  int tid = threadIdx.x, wid = tid >> 6, lane = tid & 63, lr = lane & 15, lg = lane >> 4;
  int bb = bh >> 3, h = bh & 7;
  const unsigned short* Kg = Kb + (size_t)bh * 16384;
  const unsigned short* Vg = Vtb + (size_t)bh * 16384;
#pragma unroll
  for (int c = 0; c < 4; ++c) {
    int d = (wid * 4 + c) * 64 + lane;
    int kr = d >> 3, kc = (d & 7) ^ (kr & 7);
    async16(Kg + (size_t)kr * 64 + kc * 8, Ks + (wid * 4 + c) * 512);
    int vr = d >> 5, vc = (d & 31) ^ ((vr & 7) << 2);
    async16(Vg + (size_t)vr * 256 + vc * 8, Vs + (wid * 4 + c) * 512);
  }
  __syncthreads();   // vmcnt(0) drain + barrier

#pragma unroll
  for (int cc = 0; cc < 2; ++cc) {
    int ci = cc ? (15 - wid) : wid;
    int t0 = ci * 16, trow = t0 + lr;
    int ntV = ci + 1;
    int ntE = (ntV + 1) & ~1;
    int nk32 = ntE >> 1;
    const unsigned short* qsrc = Qb + (size_t)bh * 16384 + (size_t)(t0 + lr) * 64 + lg * 8;
    bf16x8 bq0 = *(const bf16x8*)qsrc;
    bf16x8 bq1 = *(const bf16x8*)(qsrc + 32);
    f32x4 acc[16];
#pragma unroll
    for (int nt = 0; nt < 16; ++nt)
      if (nt < ntE) acc[nt] = (f32x4){0.f, 0.f, 0.f, 0.f};
#pragma unroll
    for (int nt = 0; nt < 16; ++nt)
      if (nt < ntV) {
        int row = nt * 16 + lr;
        bf16x8 ak0 = *(const bf16x8*)&Ks[row * 64 + ((0 + lg) ^ (lr & 7)) * 8];
        acc[nt] = __builtin_amdgcn_mfma_f32_16x16x32_bf16(ak0, bq0, acc[nt], 0, 0, 0);
        bf16x8 ak1 = *(const bf16x8*)&Ks[row * 64 + ((4 + lg) ^ (lr & 7)) * 8];
        acc[nt] = __builtin_amdgcn_mfma_f32_16x16x32_bf16(ak1, bq1, acc[nt], 0, 0, 0);
      }
    // acc[nt][r] = S[t=trow][s=nt*16+lg*4+r]
    float m = -3.0e38f;
#pragma unroll
    for (int nt = 0; nt < 16; ++nt)
      if (nt < ntE) {
#pragma unroll
        for (int r = 0; r < 4; ++r) {
          float v = acc[nt][r] * 0.125f;
          if (nt * 16 + lg * 4 + r > trow) v = -1.0e30f;
          acc[nt][r] = v;
          m = fmaxf(m, v);
        }
      }
    m = fmaxf(m, __shfl_xor(m, 16));
    m = fmaxf(m, __shfl_xor(m, 32));
    float s = 0.f;
    bf16x4 pk[16];
#pragma unroll
    for (int nt = 0; nt < 16; ++nt)
      if (nt < ntE) {
#pragma unroll
        for (int r = 0; r < 4; ++r) {
          float p = __expf(acc[nt][r] - m);
          s += p;
          pk[nt][r] = (__bf16)p;
        }
      }
    s += __shfl_xor(s, 16);
    s += __shfl_xor(s, 32);
    float inv = 1.0f / s;
    // prologue: write slot for k32=0 (nt 0,1)
    *(bf16x4*)&Ps[wid][lr][lg * 4] = pk[0];
    *(bf16x4*)&Ps[wid][lr][16 + lg * 4] = pk[1];
    f32x4 aco[4];
#pragma unroll
    for (int vt = 0; vt < 4; ++vt) aco[vt] = (f32x4){0.f, 0.f, 0.f, 0.f};
#pragma unroll
    for (int k32 = 0; k32 < 8; ++k32)
      if (k32 < nk32) {
        // read current pair (in-order FIFO: follows the write that produced it)
        bf16x8 pb = *(const bf16x8*)&Ps[wid][lr][lg * 8];
        // write next pair (WAR safe: read is older in the wave's LDS queue)
        if (k32 + 1 < nk32) {
          *(bf16x4*)&Ps[wid][lr][lg * 4] = pk[2 * k32 + 2];
          *(bf16x4*)&Ps[wid][lr][16 + lg * 4] = pk[2 * k32 + 3];
        }
#pragma unroll
        for (int vt = 0; vt < 4; ++vt) {
          int row = vt * 16 + lr;
          bf16x8 av = *(const bf16x8*)&Vs[row * 256 + (((k32 * 4 + lg) ^ ((lr & 7) << 2)) * 8)];
          aco[vt] = __builtin_amdgcn_mfma_f32_16x16x32_bf16(av, pb, aco[vt], 0, 0, 0);
        }
      }
    // aco[vt][r] = O[t=trow][hd=vt*16+lg*4+r]
    unsigned short* obase = Ob + (size_t)(bb * 256 + trow) * 512 + h * 64 + lg * 4;
#pragma unroll
    for (int vt = 0; vt < 4; ++vt) {
      bf16x4 ov;
#pragma unroll
      for (int r = 0; r < 4; ++r) ov[r] = (__bf16)(aco[vt][r] * inv);
      *(bf16x4*)(obase + vt * 16) = ov;
    }
  }
}

extern "C" void kernel_launch(void* const* d_in, const int* in_sizes, int n_in,
                              void* d_out, int out_size, void* d_ws, size_t ws_size,
                              hipStream_t stream) {
  (void)in_sizes; (void)n_in; (void)out_size; (void)ws_size;
  const float* x = (const float*)d_in[0];
  const float* Wq = (const float*)d_in[1];
  const float* Wk = (const float*)d_in[2];
  const float* Wv = (const float*)d_in[3];
  const float* Wo = (const float*)d_in[4];
  const float* bo = (const float*)d_in[5];
  float* out = (float*)d_out;
  char* ws = (char*)d_ws;
  const size_t MB = 1024 * 1024;
  unsigned short* Qb = (unsigned short*)(ws);             // 32 MB
  unsigned short* Kb = (unsigned short*)(ws + 32 * MB);   // 32 MB
  unsigned short* Vtb = (unsigned short*)(ws + 64 * MB);  // 32 MB
  unsigned short* xb = (unsigned short*)(ws + 96 * MB);   // 32 MB (reused as attn out)
  unsigned short* Wqt = (unsigned short*)(ws + 128 * MB); // [512][512]; Wkt follows -> [1024][512]
  unsigned short* Wkt = Wqt + 262144;
  unsigned short* Wvt = Wkt + 262144;
  unsigned short* Wot = Wvt + 262144;

  hipLaunchKernelGGL(k_convert_x, dim3(8192), dim3(256), 0, stream, x, xb);
  hipLaunchKernelGGL(k_transpose_w3, dim3(1, 8, 24), dim3(256), 0, stream, Wq, Wk, Wv, Wqt);
  hipLaunchKernelGGL(k_transpose_w, dim3(8, 8, 1), dim3(256), 0, stream, Wo, Wot, 512, 512);
  // QK projection: B = [Wqt;Wkt] = [1024][512]
  hipLaunchKernelGGL((k_gemmP<0>), dim3(512), dim3(512), 0, stream,
                     xb, Wqt, Qb, Kb, (const float*)nullptr, (float*)nullptr);
  // V projection -> V^T
  hipLaunchKernelGGL((k_gemmP<2>), dim3(256), dim3(512), 0, stream,
                     xb, Wvt, Vtb, (unsigned short*)nullptr, (const float*)nullptr, (float*)nullptr);
  hipLaunchKernelGGL(k_attn2, dim3(1024), dim3(512), 0, stream, Qb, Kb, Vtb, xb);
  hipLaunchKernelGGL((k_gemmP<1>), dim3(256), dim3(512), 0, stream,
                     xb, Wot, (unsigned short*)nullptr, (unsigned short*)nullptr, bo, out);
}